// Round 4
// baseline (517.394 us; speedup 1.0000x reference)
//
#include <hip/hip_runtime.h>

// MinibatchDiscrimination — all-pairs L1 distance + concat.
//   inputs: [N=1024, D=512] fp32
//   out[i, 0:512]   = inputs[i, :]
//   out[i, 512 + j] = sum_d |x[i,d] - x[j,d]|
// out is [1024, 1536] fp32 row-major.
//
// R4: symmetric tri-tiling + 8x8 micro-tile + cross-block k-split + atomics.
//   - 64x64 output tiles, only bi<=bj pairs (136); mirror via atomicAdd.
//   - k split into 16 chunks of 32 across blockIdx.y -> 2176 one-wave blocks
//     (~8.5/CU = 2+ waves/SIMD), each block: stage 17KB LDS, one barrier,
//     32k x 128 VALU from LDS, 64(+64 mirror) atomicAdds.
//   - LDS k-major [32][68]: fragment reads are aligned ds_read_b128,
//     2-way bank alias (free); staging writes 4-way (negligible volume).
//   - init kernel zeroes l1 region (atomics accumulate) + copies inputs.

#define N_PTS 1024
#define D_DIM 512
#define OUTW  1536
#define TS    64
#define KC    32
#define NT    (N_PTS / TS)          // 16 tiles per side
#define NKZ   (D_DIM / KC)          // 16 k-chunks
#define NPAIR (NT * (NT + 1) / 2)   // 136 tri tile-pairs
#define SROW  68                    // LDS row stride: 16B-aligned frags, banks ok

// -------- init: copy inputs into out[:, 0:512], zero out[:, 512:] ---------
__global__ __launch_bounds__(256) void init_out_kernel(const float* __restrict__ x,
                                                       float* __restrict__ out) {
    int idx = blockIdx.x * 256 + threadIdx.x;
    if (idx < N_PTS * D_DIM / 4) {
        int i = idx >> 7, d = idx & 127;          // 128 float4 per input row
        *(float4*)&out[(size_t)i * OUTW + (d << 2)] =
            *(const float4*)&x[(size_t)i * D_DIM + (d << 2)];
    } else {
        int z = idx - N_PTS * D_DIM / 4;
        int i = z >> 8, j = z & 255;              // 256 float4 per l1 row
        *(float4*)&out[(size_t)i * OUTW + D_DIM + (j << 2)] =
            make_float4(0.f, 0.f, 0.f, 0.f);
    }
}

// -------- tri-tile all-pairs L1 partial (one 32-k chunk) ------------------
__global__ __launch_bounds__(64, 2) void l1_pairs_kernel(const float* __restrict__ x,
                                                         float* __restrict__ out) {
    __shared__ __align__(16) float As[KC][SROW];
    __shared__ __align__(16) float Bs[KC][SROW];

    // decode triangular pair index -> (bi, bj), bi <= bj
    int p = blockIdx.x, bi = 0, rem = NT;
    while (p >= rem) { p -= rem; ++bi; rem = NT - bi; }
    const int bj   = bi + p;
    const int k0   = blockIdx.y * KC;
    const int rowA = bi * TS;
    const int colB = bj * TS;

    const int l = threadIdx.x;

    // ---- stage A and B tiles, transposed to k-major ----
    {
        const int iq = l >> 3;                    // row-octet offset 0..7
        const int c  = l & 7;                     // float4 slot in k-chunk
        #pragma unroll
        for (int q = 0; q < 8; ++q) {
            const int i = (q << 3) + iq;          // tile row 0..63
            const float4 va = *(const float4*)&x[(size_t)(rowA + i) * D_DIM + k0 + (c << 2)];
            const float4 vb = *(const float4*)&x[(size_t)(colB + i) * D_DIM + k0 + (c << 2)];
            As[(c << 2) + 0][i] = va.x; As[(c << 2) + 1][i] = va.y;
            As[(c << 2) + 2][i] = va.z; As[(c << 2) + 3][i] = va.w;
            Bs[(c << 2) + 0][i] = vb.x; Bs[(c << 2) + 1][i] = vb.y;
            Bs[(c << 2) + 2][i] = vb.z; Bs[(c << 2) + 3][i] = vb.w;
        }
    }
    __syncthreads();

    const int tx = l & 7;                          // j-fragment (8 cols)
    const int ty = l >> 3;                         // i-fragment (8 rows)
    const float* ap = &As[0][ty << 3];
    const float* bp = &Bs[0][tx << 3];

    float acc[8][8] = {};

    #pragma unroll 4
    for (int k = 0; k < KC; ++k) {
        float av[8], bv[8];
        *(float4*)&av[0] = *(const float4*)(ap + k * SROW);      // ds_read_b128
        *(float4*)&av[4] = *(const float4*)(ap + k * SROW + 4);
        *(float4*)&bv[0] = *(const float4*)(bp + k * SROW);
        *(float4*)&bv[4] = *(const float4*)(bp + k * SROW + 4);
        #pragma unroll
        for (int r = 0; r < 8; ++r) {
            #pragma unroll
            for (int cc = 0; cc < 8; ++cc)
                acc[r][cc] += fabsf(av[r] - bv[cc]);
        }
    }

    // ---- accumulate partials into out (and mirror for off-diagonal) ----
    #pragma unroll
    for (int r = 0; r < 8; ++r) {
        float* orow = &out[(size_t)(rowA + (ty << 3) + r) * OUTW + D_DIM + colB + (tx << 3)];
        #pragma unroll
        for (int cc = 0; cc < 8; ++cc)
            atomicAdd(&orow[cc], acc[r][cc]);
    }
    if (bi != bj) {
        #pragma unroll
        for (int cc = 0; cc < 8; ++cc) {
            float* orow = &out[(size_t)(colB + (tx << 3) + cc) * OUTW + D_DIM + rowA + (ty << 3)];
            #pragma unroll
            for (int r = 0; r < 8; ++r)
                atomicAdd(&orow[r], acc[r][cc]);
        }
    }
}

extern "C" void kernel_launch(void* const* d_in, const int* in_sizes, int n_in,
                              void* d_out, int out_size, void* d_ws, size_t ws_size,
                              hipStream_t stream) {
    const float* x   = (const float*)d_in[0];
    float*       out = (float*)d_out;

    // copy 131072 f4 + zero 262144 f4 = 393216 f4 -> 1536 blocks x 256
    hipLaunchKernelGGL(init_out_kernel, dim3(1536), dim3(256), 0, stream, x, out);

    hipLaunchKernelGGL(l1_pairs_kernel, dim3(NPAIR, NKZ), dim3(64), 0, stream, x, out);
}

// Round 5
// 42.249 us; speedup vs baseline: 12.2464x; 12.2464x over previous
//
#include <hip/hip_runtime.h>

// MinibatchDiscrimination — all-pairs L1 distance + concat.
//   inputs: [N=1024, D=512] fp32
//   out[i, 0:512]   = inputs[i, :]
//   out[i, 512 + j] = sum_d |x[i,d] - x[j,d]|
// out is [1024, 1536] fp32 row-major.
//
// R5: single kernel. 256 blocks (one 64x64 tile each), 512 threads = 8 waves.
//   - In-block k-split: wave w owns k in [64w, 64w+64), 2 chunks of 32,
//     staged k-major [32][68] in a WAVE-PRIVATE 17.4KB LDS region
//     (8 x 4352 floats = 139264 B total). Private => no barrier in main loop;
//     wave-local lgkmcnt(0) orders own-wave LDS write->read (in-wave idiom).
//   - 8x8 micro-tile per thread from aligned ds_read_b128 (R4-proven
//     conflict-free pattern: 2-way/broadcast only).
//   - Reduction: each wave writes its 64 partials/thread into its own region
//     (XOR col-swizzle vs 8-way banks), ONE __syncthreads, then each thread
//     sums 8 partials for 8 outputs, coalesced float4 stores. No atomics.
//   - Input passthrough (out[:, :512]) folded in: block b copies rows 4b..4b+3.

#define N_PTS 1024
#define D_DIM 512
#define OUTW  1536
#define TS    64                  // tile side
#define KW    64                  // k per wave
#define KC    32                  // k per staged chunk
#define SROW  68                  // k-major LDS row stride (aligned b128, banks ok)
#define REG   (2 * KC * SROW)     // 4352 floats: per-wave A+B region = partial region

__global__ __launch_bounds__(512, 2) void l1_fused_kernel(const float* __restrict__ x,
                                                          float* __restrict__ out) {
    __shared__ __align__(16) float S[8 * REG];   // 139264 B

    const int t    = threadIdx.x;
    const int l    = t & 63;
    const int w    = __builtin_amdgcn_readfirstlane(t >> 6);   // wave id 0..7
    const int rowA = blockIdx.y * TS;
    const int colB = blockIdx.x * TS;

    // ---- fused input passthrough: block copies 4 rows of x into out[:, :512]
    {
        const int bid = blockIdx.y * 16 + blockIdx.x;
        const int i   = bid * 4 + (t >> 7);      // 4 rows per block
        const int d4  = t & 127;                 // 128 float4 per row
        *(float4*)&out[(size_t)i * OUTW + (d4 << 2)] =
            *(const float4*)&x[(size_t)i * D_DIM + (d4 << 2)];
    }

    float* Aw = &S[w * REG];            // wave-private A: [KC][SROW]
    float* Bw = Aw + KC * SROW;         // wave-private B: [KC][SROW]

    const int tx = l & 7;               // j-fragment
    const int ty = l >> 3;              // i-fragment
    const int iq = l >> 3;              // staging row-octet offset
    const int c  = l & 7;               // staging float4 slot (KC=32 -> 8 slots)

    float acc[8][8] = {};

    #pragma unroll
    for (int ch = 0; ch < 2; ++ch) {
        const int k0 = w * KW + ch * KC;

        // ---- wave-private staging: A rows rowA+*, B rows colB+*, k-major ----
        #pragma unroll
        for (int q = 0; q < 8; ++q) {
            const int i = (q << 3) + iq;
            const float4 va = *(const float4*)&x[(size_t)(rowA + i) * D_DIM + k0 + (c << 2)];
            const float4 vb = *(const float4*)&x[(size_t)(colB + i) * D_DIM + k0 + (c << 2)];
            Aw[((c << 2) + 0) * SROW + i] = va.x;
            Aw[((c << 2) + 1) * SROW + i] = va.y;
            Aw[((c << 2) + 2) * SROW + i] = va.z;
            Aw[((c << 2) + 3) * SROW + i] = va.w;
            Bw[((c << 2) + 0) * SROW + i] = vb.x;
            Bw[((c << 2) + 1) * SROW + i] = vb.y;
            Bw[((c << 2) + 2) * SROW + i] = vb.z;
            Bw[((c << 2) + 3) * SROW + i] = vb.w;
        }
        // wave-local visibility: own-wave LDS writes -> own-wave reads
        asm volatile("s_waitcnt lgkmcnt(0)" ::: "memory");

        const float* ap = Aw + (ty << 3);
        const float* bp = Bw + (tx << 3);

        #pragma unroll 4
        for (int k = 0; k < KC; ++k) {
            float av[8], bv[8];
            *(float4*)&av[0] = *(const float4*)(ap + k * SROW);       // b128, 2-way
            *(float4*)&av[4] = *(const float4*)(ap + k * SROW + 4);
            *(float4*)&bv[0] = *(const float4*)(bp + k * SROW);
            *(float4*)&bv[4] = *(const float4*)(bp + k * SROW + 4);
            #pragma unroll
            for (int r = 0; r < 8; ++r) {
                #pragma unroll
                for (int cc = 0; cc < 8; ++cc)
                    acc[r][cc] += fabsf(av[r] - bv[cc]);
            }
        }
        // WAR to next chunk's staging is ordered by compiler-inserted lgkmcnt
    }

    // ---- write partials into own (now-free) region, XOR swizzle vs banks ----
    {
        float* P = &S[w * REG];         // [64 rows][SROW], rows = tile i
        #pragma unroll
        for (int r = 0; r < 8; ++r) {
            const int row = (ty << 3) + r;
            const int g   = tx ^ ((row >> 2) & 7);     // col-octet swizzle
            *(float4*)&P[row * SROW + (g << 3) + 0] =
                make_float4(acc[r][0], acc[r][1], acc[r][2], acc[r][3]);
            *(float4*)&P[row * SROW + (g << 3) + 4] =
                make_float4(acc[r][4], acc[r][5], acc[r][6], acc[r][7]);
        }
    }
    __syncthreads();

    // ---- each thread: sum 8 partials for its 8 outputs, store coalesced ----
    {
        const int row = t >> 3;                        // 0..63
        const int g   = t & 7;                         // col-octet
        const int gs  = g ^ ((row >> 2) & 7);          // un-swizzle
        float4 s0 = make_float4(0.f, 0.f, 0.f, 0.f);
        float4 s1 = make_float4(0.f, 0.f, 0.f, 0.f);
        #pragma unroll
        for (int p = 0; p < 8; ++p) {
            const float* P = &S[p * REG + row * SROW + (gs << 3)];
            const float4 a = *(const float4*)&P[0];
            const float4 b = *(const float4*)&P[4];
            s0.x += a.x; s0.y += a.y; s0.z += a.z; s0.w += a.w;
            s1.x += b.x; s1.y += b.y; s1.z += b.z; s1.w += b.w;
        }
        float* orow = &out[(size_t)(rowA + row) * OUTW + D_DIM + colB + (g << 3)];
        *(float4*)&orow[0] = s0;
        *(float4*)&orow[4] = s1;
    }
}

extern "C" void kernel_launch(void* const* d_in, const int* in_sizes, int n_in,
                              void* d_out, int out_size, void* d_ws, size_t ws_size,
                              hipStream_t stream) {
    const float* x   = (const float*)d_in[0];
    float*       out = (float*)d_out;
    hipLaunchKernelGGL(l1_fused_kernel, dim3(N_PTS / TS, N_PTS / TS), dim3(512),
                       0, stream, x, out);
}